// Round 13
// baseline (465.804 us; speedup 1.0000x reference)
//
#include <hip/hip_runtime.h>
#include <hip/hip_bf16.h>
#include <math.h>

#define Bb 4
#define Nn 2048
#define DIMd 128
#define Kk 32
#define H1 530      // EDGE_IN*2
#define PW2 530     // P table width (i-part only)
#define MD 16
#define NDH 256
#define NDI 144
#define TOPK_BLKS (Bb*Nn/4)     // 2048
#define PMAT_BLKS (Bb*Nn/32)    // 256

typedef float f32x2 __attribute__((ext_vector_type(2)));
typedef float f32x4 __attribute__((ext_vector_type(4)));
typedef short s16x8 __attribute__((ext_vector_type(8)));

__device__ __forceinline__ unsigned short f2bf(float f){
    union { float f; unsigned u; } v; v.f = f;
    unsigned r = v.u + 0x7FFFu + ((v.u >> 16) & 1u);
    return (unsigned short)(r >> 16);
}
__device__ __forceinline__ float silu_f(float x){
    float e = __builtin_amdgcn_exp2f(x * -1.442695041f);
    return x * __builtin_amdgcn_rcpf(1.0f + e);
}
__device__ __forceinline__ f32x2 silu2(f32x2 x){
    float e0 = __builtin_amdgcn_exp2f(x[0] * -1.442695041f);
    float e1 = __builtin_amdgcn_exp2f(x[1] * -1.442695041f);
    f32x2 r;
    r[0] = x[0] * __builtin_amdgcn_rcpf(1.0f + e0);
    r[1] = x[1] * __builtin_amdgcn_rcpf(1.0f + e1);
    return r;
}
__device__ __forceinline__ unsigned cvt_pk_bf16(float a, float b){
    unsigned r;
    asm("v_cvt_pk_bf16_f32 %0, %1, %2" : "=v"(r) : "v"(a), "v"(b));
    return r;
}

// ---------------- Kernel F: build all MFMA fragments (bf16, fragment-linear) -----------------
__global__ __launch_bounds__(256) void fragw_kernel(const float* __restrict__ eW1,
        const float* __restrict__ eW2,
        unsigned short* __restrict__ W1F, unsigned short* __restrict__ WPF,
        unsigned short* __restrict__ W2F2){
    int i0 = blockIdx.x * 256 + threadIdx.x;
    int stride = gridDim.x * 256;
    for (int i = i0; i < 34*5*512; i += stride){
        int j = i & 7, lane = (i >> 3) & 63, t = i >> 9;
        int ks = t % 5, nt = t / 5;
        int cg = nt*16 + (lane & 15);
        int k = ks*32 + ((lane >> 4) << 3) + j;
        float v = 0.f;
        if (cg < H1){
            if (k < 128) v = eW1[(size_t)(128+k)*H1 + cg];
            else if (k < 137) v = eW1[(size_t)(256+(k-128))*H1 + cg];
        }
        W1F[i] = f2bf(v);
    }
    for (int i = i0; i < 34*4*512; i += stride){
        int j = i & 7, lane = (i >> 3) & 63, t = i >> 9;
        int ks = t & 3, nt = t >> 2;
        int cg = nt*16 + (lane & 15);
        int k = ks*32 + ((lane >> 4) << 3) + j;
        float v = (cg < H1) ? eW1[(size_t)k*H1 + cg] : 0.f;
        WPF[i] = f2bf(v);
    }
    for (int i = i0; i < 34*512; i += stride){
        int j = i & 7, lane = (i >> 3) & 63, nt = i >> 9;
        int kl = ((lane >> 4) << 3) + j;       // 0..31, valid < 16
        int col = lane & 15;                   // f (A-row) = output feature
        int row = nt*16 + kl;
        float v = (kl < 16 && row < H1) ? eW2[(size_t)row*MD + col] : 0.f;
        W2F2[i] = f2bf(v);
    }
}

// ---------------- Kernel P: fused topk (blocks 0..2047, LDS-staged coors) + pmat -------------
__global__ __launch_bounds__(256) void prep_kernel(const float* __restrict__ coors,
        const float* __restrict__ feats,
        const unsigned short* __restrict__ WPF, const float* __restrict__ eb1,
        int* __restrict__ idx_ws, float* __restrict__ dv_ws, float* __restrict__ P){
    __shared__ float cs[Nn*3];     // 24576 B, topk branch only
    int bid = blockIdx.x;
    int tid = threadIdx.x;
    if (bid < TOPK_BLKS){
        int w = tid >> 6, lane = tid & 63;
        int node = bid * 4 + w;
        int b = node >> 11;
        const float* cbp = coors + (size_t)b * Nn * 3;
        for (int t = tid; t < Nn*3; t += 256) cs[t] = cbp[t];
        __syncthreads();
        float cx = cs[(node & (Nn-1))*3+0], cy = cs[(node & (Nn-1))*3+1], cz = cs[(node & (Nn-1))*3+2];
        float d[32];
        #pragma unroll
        for (int t = 0; t < 32; t++){
            int j = t*64 + lane;
            float dx = cx - cs[j*3+0], dy = cy - cs[j*3+1], dz = cz - cs[j*3+2];
            d[t] = dx*dx + dy*dy + dz*dz;
        }
        float md = d[0]; int mj = lane;
        #pragma unroll
        for (int t = 1; t < 32; t++){
            int jt = t*64 + lane;
            if (d[t] < md){ md = d[t]; mj = jt; }
        }
        for (int r = 0; r < Kk; r++){
            float bd = md; int bj = mj;
            #pragma unroll
            for (int off = 32; off; off >>= 1){
                float d2 = __shfl_xor(bd, off); int j2 = __shfl_xor(bj, off);
                if (d2 < bd || (d2 == bd && j2 < bj)){ bd = d2; bj = j2; }
            }
            if (lane == 0){
                idx_ws[node*Kk + r] = bj;
                dv_ws[node*Kk + r] = bd;
            }
            if (mj == bj){
                md = 3.4e38f; mj = 0x7fffffff;
                #pragma unroll
                for (int t = 0; t < 32; t++){
                    int jt = t*64 + lane;
                    if (jt == bj) d[t] = 3.4e38f;
                    if (d[t] < md){ md = d[t]; mj = jt; }
                }
            }
        }
    } else {
        int wid = tid >> 6, lane = tid & 63;
        int node0 = (bid - TOPK_BLKS) * 32;
        int kg = (lane >> 4) * 8;
        s16x8 af[2][4];
        #pragma unroll
        for (int m = 0; m < 2; m++){
            const float* fr = feats + (size_t)(node0 + m*16 + (lane & 15)) * DIMd;
            #pragma unroll
            for (int ks = 0; ks < 4; ks++){
                f32x4 lo = *(const f32x4*)(fr + ks*32 + kg);
                f32x4 hi = *(const f32x4*)(fr + ks*32 + kg + 4);
                union { s16x8 v; unsigned u[4]; } pk;
                pk.u[0] = cvt_pk_bf16(lo[0], lo[1]); pk.u[1] = cvt_pk_bf16(lo[2], lo[3]);
                pk.u[2] = cvt_pk_bf16(hi[0], hi[1]); pk.u[3] = cvt_pk_bf16(hi[2], hi[3]);
                af[m][ks] = pk.v;
            }
        }
        const s16x8* WPFv = (const s16x8*)WPF;
        for (int nt = wid; nt < 34; nt += 4){
            f32x4 acc0 = {0,0,0,0}, acc1 = {0,0,0,0};
            #pragma unroll
            for (int ks = 0; ks < 4; ks++){
                s16x8 bb = WPFv[(nt*4 + ks)*64 + lane];
                acc0 = __builtin_amdgcn_mfma_f32_16x16x32_bf16(af[0][ks], bb, acc0, 0, 0, 0);
                acc1 = __builtin_amdgcn_mfma_f32_16x16x32_bf16(af[1][ks], bb, acc1, 0, 0, 0);
            }
            int cg = nt*16 + (lane & 15);
            if (cg < H1){
                float b = eb1[cg];
                int r0 = (lane >> 4) * 4;
                #pragma unroll
                for (int r = 0; r < 4; r++){
                    P[(size_t)(node0 + r0 + r)*PW2 + cg]      = acc0[r] + b;
                    P[(size_t)(node0 + 16 + r0 + r)*PW2 + cg] = acc1[r] + b;
                }
            }
        }
    }
}

// ---------------- Kernel C: edge main loop (r12 shape, 8 blocks/CU) --------------------------
// VGPR need ~40-56 < 64 cap at (256,8); LDS 13.3 KB -> 8 blocks/CU (106 KB)
__global__ __launch_bounds__(256, 8) void edge_kernel(
        const float* __restrict__ feats, const float* __restrict__ eb2,
        const float* __restrict__ P, const unsigned short* __restrict__ W1F,
        const unsigned short* __restrict__ W2F2,
        const int* __restrict__ idx_ws, const float* __restrict__ dv_ws,
        float* __restrict__ m_ws){
    __shared__ float Pi_lds[544];                           // 2176 B
    __shared__ __align__(16) unsigned short aenc[Kk][32];   // 2048 B
    __shared__ int js[Kk];
    __shared__ float m_red[4][Kk][MD+1];                    // 8704 B  -> ~13.1 KB

    int node = blockIdx.x; int tid = threadIdx.x;
    int b = node >> 11;
    int wid = tid >> 6, lane = tid & 63;

    const float* Pn = P + (size_t)node*PW2;
    Pi_lds[tid]       = Pn[tid];
    { int c = tid + 256; Pi_lds[c] = (c < PW2) ? Pn[c] : 0.f; }
    if (tid < 32){ int c = 512 + tid; Pi_lds[c] = (c < PW2) ? Pn[c] : 0.f; }
    if (tid < Kk){
        int j = idx_ws[node*Kk + tid];
        float dv = dv_ws[node*Kk + tid];
        js[tid] = j;
        unsigned short e[9];
        e[0] = f2bf(sinf(dv));        e[1] = f2bf(sinf(dv*0.5f));
        e[2] = f2bf(sinf(dv*0.25f));  e[3] = f2bf(sinf(dv*0.125f));
        e[4] = f2bf(cosf(dv));        e[5] = f2bf(cosf(dv*0.5f));
        e[6] = f2bf(cosf(dv*0.25f));  e[7] = f2bf(cosf(dv*0.125f));
        e[8] = f2bf(dv);
        #pragma unroll
        for (int q = 0; q < 9; q++) aenc[tid][q] = e[q];
        #pragma unroll
        for (int q = 9; q < 32; q++) aenc[tid][q] = 0;
    }
    __syncthreads();

    // per-lane fragment of [feats_j | enc] for neighbor = lane&15 (+16 for half 1);
    // used as MFMA *B* operand (col = neighbor) — same per-lane layout as A.
    int kg = (lane >> 4) * 8;
    int grp = lane >> 4, n16 = lane & 15;
    s16x8 af[2][5];
    #pragma unroll
    for (int m = 0; m < 2; m++){
        int row = m*16 + n16;
        int jgl = (b << 11) + js[row];
        const float* fr = feats + (size_t)jgl * DIMd;
        #pragma unroll
        for (int ks = 0; ks < 4; ks++){
            f32x4 lo = *(const f32x4*)(fr + ks*32 + kg);
            f32x4 hi = *(const f32x4*)(fr + ks*32 + kg + 4);
            union { s16x8 v; unsigned u[4]; } pk;
            pk.u[0] = cvt_pk_bf16(lo[0], lo[1]); pk.u[1] = cvt_pk_bf16(lo[2], lo[3]);
            pk.u[2] = cvt_pk_bf16(hi[0], hi[1]); pk.u[3] = cvt_pk_bf16(hi[2], hi[3]);
            af[m][ks] = pk.v;
        }
        af[m][4] = *(const s16x8*)(&aenc[row][kg]);
    }

    int s1 = ((grp & 1) << 1) | (grp >> 1);   // 0,1,2,3 -> 0,2,1,3
    int s2 = s1 ^ 1;
    int addr1 = ((s1 << 4) | n16) << 2;
    int addr2 = ((s2 << 4) | n16) << 2;

    // Fused GEMM1' (C'[cg][n]) + silu + bpermute-transpose + GEMM2 (m^T[f][n])
    const s16x8* W1Fv  = (const s16x8*)W1F;
    const s16x8* W2F2v = (const s16x8*)W2F2;
    f32x4 macc0 = {0,0,0,0}, macc1 = {0,0,0,0};
    for (int nt = wid; nt < 34; nt += 4){
        f32x4 acc0 = {0,0,0,0}, acc1 = {0,0,0,0};
        #pragma unroll
        for (int ks = 0; ks < 5; ks++){
            s16x8 aw = W1Fv[(nt*5 + ks)*64 + lane];     // A: rows = cg tile
            acc0 = __builtin_amdgcn_mfma_f32_16x16x32_bf16(aw, af[0][ks], acc0, 0, 0, 0);
            acc1 = __builtin_amdgcn_mfma_f32_16x16x32_bf16(aw, af[1][ks], acc1, 0, 0, 0);
        }
        s16x8 w2a = W2F2v[nt*64 + lane];                // A: rows = f, k>=16 zeroed
        int cgb = nt*16 + grp*4;
        float x0[4], x1[4];
        #pragma unroll
        for (int r = 0; r < 4; r++){
            float pic = Pi_lds[cgb + r];                // group-uniform broadcast read
            x0[r] = silu_f(acc0[r] + pic);
            x1[r] = silu_f(acc1[r] + pic);
        }
        unsigned p00 = cvt_pk_bf16(x0[0], x0[1]), p01 = cvt_pk_bf16(x0[2], x0[3]);
        unsigned p10 = cvt_pk_bf16(x1[0], x1[1]), p11 = cvt_pk_bf16(x1[2], x1[3]);
        union { s16x8 v; int u[4]; } b0, b1;
        b0.u[0] = __builtin_amdgcn_ds_bpermute(addr1, (int)p00);
        b0.u[1] = __builtin_amdgcn_ds_bpermute(addr1, (int)p01);
        b0.u[2] = __builtin_amdgcn_ds_bpermute(addr2, (int)p00);
        b0.u[3] = __builtin_amdgcn_ds_bpermute(addr2, (int)p01);
        b1.u[0] = __builtin_amdgcn_ds_bpermute(addr1, (int)p10);
        b1.u[1] = __builtin_amdgcn_ds_bpermute(addr1, (int)p11);
        b1.u[2] = __builtin_amdgcn_ds_bpermute(addr2, (int)p10);
        b1.u[3] = __builtin_amdgcn_ds_bpermute(addr2, (int)p11);
        macc0 = __builtin_amdgcn_mfma_f32_16x16x32_bf16(w2a, b0.v, macc0, 0, 0, 0);
        macc1 = __builtin_amdgcn_mfma_f32_16x16x32_bf16(w2a, b1.v, macc1, 0, 0, 0);
    }
    #pragma unroll
    for (int r = 0; r < 4; r++){
        m_red[wid][n16][grp*4 + r]      = macc0[r];
        m_red[wid][16 + n16][grp*4 + r] = macc1[r];
    }
    __syncthreads();
    #pragma unroll
    for (int t = tid; t < Kk*MD; t += 256){
        int n = t >> 4, f = t & 15;
        float s = m_red[0][n][f] + m_red[1][n][f] + m_red[2][n][f] + m_red[3][n][f];
        m_ws[(size_t)node*(Kk*MD) + t] = silu_f(s + eb2[f]);
    }
}

// ---------------- Kernel N: finish — m_ws read direct from L2, 19.2 KB LDS, 8 blocks/CU ------
__global__ __launch_bounds__(256, 8) void finish_kernel(const float* __restrict__ feats,
        const float* __restrict__ coors,
        const float* __restrict__ m_ws, const int* __restrict__ idx_ws,
        const float* __restrict__ cW1, const float* __restrict__ cb1,
        const float* __restrict__ cW2, const float* __restrict__ cb2,
        const float* __restrict__ nW1, const float* __restrict__ nb1,
        const float* __restrict__ nW2, const float* __restrict__ nb2,
        float* __restrict__ out, float* __restrict__ coors_out){
    __shared__ float insT[NDI][12];      // 6912 B
    __shared__ float hsdT[NDH][12];      // 12288 B -> 19.2 KB
    int tid = threadIdx.x;
    int node0 = blockIdx.x * 8;
    for (int t = tid; t < 8*DIMd; t += 256)
        insT[t & 127][t >> 7] = feats[(size_t)node0*DIMd + t];
    // one edge per thread
    int nl = tid >> 5, n = tid & 31;
    int node = node0 + nl;
    int b = node >> 11;
    int j = idx_ws[node*Kk + n];
    int jg = (b << 11) + j;
    float rx = coors[node*3+0] - coors[jg*3+0];
    float ry = coors[node*3+1] - coors[jg*3+1];
    float rz = coors[node*3+2] - coors[jg*3+2];
    // mi directly from L2-hot m_ws
    if (tid < 128){
        int m = tid >> 4, f = tid & 15;
        const float* mr = m_ws + (size_t)(node0+m)*(Kk*MD) + f;
        float s = 0.f;
        #pragma unroll
        for (int q = 0; q < Kk; q++) s += mr[q*MD];
        insT[DIMd + f][m] = s;
    }
    // cw MLP: this thread's edge row (16 consecutive f32, coalesced per thread)
    const float* mvp = m_ws + (size_t)node*(Kk*MD) + n*MD;
    f32x4 mv0 = *(const f32x4*)(mvp);
    f32x4 mv1 = *(const f32x4*)(mvp + 4);
    f32x4 mv2 = *(const f32x4*)(mvp + 8);
    f32x4 mv3 = *(const f32x4*)(mvp + 12);
    float mv[MD];
    #pragma unroll
    for (int q = 0; q < 4; q++){ mv[q] = mv0[q]; mv[4+q] = mv1[q]; mv[8+q] = mv2[q]; mv[12+q] = mv3[q]; }
    float p = 0.f;
    #pragma unroll 4
    for (int ug = 0; ug < 16; ug++){
        f32x4 a4 = *(const f32x4*)(cb1 + ug*4);
        #pragma unroll
        for (int f = 0; f < MD; f++){
            f32x4 w4 = *(const f32x4*)(cW1 + f*64 + ug*4);
            a4 += (f32x4){mv[f],mv[f],mv[f],mv[f]} * w4;
        }
        f32x4 c4 = *(const f32x4*)(cW2 + ug*4);
        p += silu_f(a4[0])*c4[0] + silu_f(a4[1])*c4[1]
           + silu_f(a4[2])*c4[2] + silu_f(a4[3])*c4[3];
    }
    float cw = p + cb2[0];
    float vx = cw*rx, vy = cw*ry, vz = cw*rz;
    #pragma unroll
    for (int off = 1; off < 32; off <<= 1){
        vx += __shfl_xor(vx, off); vy += __shfl_xor(vy, off); vz += __shfl_xor(vz, off);
    }
    if (n == 0){
        coors_out[node*3+0] = vx + coors[node*3+0];
        coors_out[node*3+1] = vy + coors[node*3+1];
        coors_out[node*3+2] = vz + coors[node*3+2];
    }
    __syncthreads();   // insT complete (staging + mi writes) before layer 1
    float bias = nb1[tid];
    f32x2 acc[4];
    #pragma unroll
    for (int q = 0; q < 4; q++) acc[q] = (f32x2){bias, bias};
    for (int k = 0; k < NDI; k++){
        float wv = nW1[(size_t)k*NDH + tid];
        f32x2 w2 = {wv, wv};
        acc[0] += *(const f32x2*)&insT[k][0] * w2;
        acc[1] += *(const f32x2*)&insT[k][2] * w2;
        acc[2] += *(const f32x2*)&insT[k][4] * w2;
        acc[3] += *(const f32x2*)&insT[k][6] * w2;
    }
    #pragma unroll
    for (int q = 0; q < 4; q++) *(f32x2*)&hsdT[tid][2*q] = silu2(acc[q]);
    __syncthreads();
    int c = tid & 127, half = tid >> 7;
    float b2 = nb2[c];
    f32x2 a0 = {b2, b2}, a1 = {b2, b2};
    for (int k = 0; k < NDH; k++){
        float wv = nW2[(size_t)k*DIMd + c];
        f32x2 w2 = {wv, wv};
        a0 += *(const f32x2*)&hsdT[k][half*4]     * w2;
        a1 += *(const f32x2*)&hsdT[k][half*4 + 2] * w2;
    }
    #pragma unroll
    for (int q = 0; q < 4; q++){
        int m = half*4 + q;
        float v = (q < 2) ? a0[q & 1] : a1[q & 1];
        out[(size_t)(node0+m)*DIMd + c] = v + feats[(size_t)(node0+m)*DIMd + c];
    }
}

extern "C" void kernel_launch(void* const* d_in, const int* in_sizes, int n_in,
                              void* d_out, int out_size, void* d_ws, size_t ws_size,
                              hipStream_t stream){
    const float* feats = (const float*)d_in[0];
    const float* coors = (const float*)d_in[1];
    const float* eW1 = (const float*)d_in[2];
    const float* eb1 = (const float*)d_in[3];
    const float* eW2 = (const float*)d_in[4];
    const float* eb2 = (const float*)d_in[5];
    const float* cW1 = (const float*)d_in[6];
    const float* cb1 = (const float*)d_in[7];
    const float* cW2 = (const float*)d_in[8];
    const float* cb2 = (const float*)d_in[9];
    const float* nW1 = (const float*)d_in[10];
    const float* nb1 = (const float*)d_in[11];
    const float* nW2 = (const float*)d_in[12];
    const float* nb2 = (const float*)d_in[13];
    float* out = (float*)d_out;                        // node_out: 4*2048*128
    float* coors_out = out + (size_t)Bb*Nn*DIMd;       // coors_out: 4*2048*3

    char* ws = (char*)d_ws;
    size_t off = 0;
    int*   idx_ws = (int*)(ws + off);   off += (1u<<20);          // 1 MB
    float* dv_ws  = (float*)(ws + off); off += (1u<<20);          // 1 MB
    float* Pd     = (float*)(ws + off); off += 17367040u;         // 8192*530*4
    float* m_ws   = (float*)(ws + off); off += 16777216u;         // 8192*512*4
    unsigned short* W1F  = (unsigned short*)(ws + off); off += 174080u;  // 34*5*512*2
    unsigned short* WPF  = (unsigned short*)(ws + off); off += 139264u;  // 34*4*512*2
    unsigned short* W2F2 = (unsigned short*)(ws + off); off += 34816u;   // 34*512*2

    fragw_kernel<<<256, 256, 0, stream>>>(eW1, eW2, W1F, WPF, W2F2);
    prep_kernel<<<TOPK_BLKS + PMAT_BLKS, 256, 0, stream>>>(coors, feats, WPF, eb1,
                                                           idx_ws, dv_ws, Pd);
    edge_kernel<<<Bb*Nn, 256, 0, stream>>>(feats, eb2, Pd, W1F, W2F2,
                                           idx_ws, dv_ws, m_ws);
    finish_kernel<<<Bb*Nn/8, 256, 0, stream>>>(feats, coors, m_ws, idx_ws,
                                               cW1, cb1, cW2, cb2,
                                               nW1, nb1, nW2, nb2, out, coors_out);
}

// Round 14
// 327.229 us; speedup vs baseline: 1.4235x; 1.4235x over previous
//
#include <hip/hip_runtime.h>
#include <hip/hip_bf16.h>
#include <math.h>

#define Bb 4
#define Nn 2048
#define DIMd 128
#define Kk 32
#define H1 530      // EDGE_IN*2
#define PW2 530     // P table width (i-part only)
#define MD 16
#define NDH 256
#define NDI 144
#define TOPK_BLKS (Bb*Nn/4)     // 2048
#define PMAT_BLKS (Bb*Nn/32)    // 256

typedef float f32x2 __attribute__((ext_vector_type(2)));
typedef float f32x4 __attribute__((ext_vector_type(4)));
typedef short s16x8 __attribute__((ext_vector_type(8)));

__device__ __forceinline__ unsigned short f2bf(float f){
    union { float f; unsigned u; } v; v.f = f;
    unsigned r = v.u + 0x7FFFu + ((v.u >> 16) & 1u);
    return (unsigned short)(r >> 16);
}
__device__ __forceinline__ float silu_f(float x){
    float e = __builtin_amdgcn_exp2f(x * -1.442695041f);
    return x * __builtin_amdgcn_rcpf(1.0f + e);
}
__device__ __forceinline__ f32x2 silu2(f32x2 x){
    float e0 = __builtin_amdgcn_exp2f(x[0] * -1.442695041f);
    float e1 = __builtin_amdgcn_exp2f(x[1] * -1.442695041f);
    f32x2 r;
    r[0] = x[0] * __builtin_amdgcn_rcpf(1.0f + e0);
    r[1] = x[1] * __builtin_amdgcn_rcpf(1.0f + e1);
    return r;
}
__device__ __forceinline__ unsigned cvt_pk_bf16(float a, float b){
    unsigned r;
    asm("v_cvt_pk_bf16_f32 %0, %1, %2" : "=v"(r) : "v"(a), "v"(b));
    return r;
}

// ---------------- Kernel F: build all MFMA fragments (bf16, fragment-linear) -----------------
__global__ __launch_bounds__(256) void fragw_kernel(const float* __restrict__ eW1,
        const float* __restrict__ eW2,
        unsigned short* __restrict__ W1F, unsigned short* __restrict__ WPF,
        unsigned short* __restrict__ W2F2){
    int i0 = blockIdx.x * 256 + threadIdx.x;
    int stride = gridDim.x * 256;
    for (int i = i0; i < 34*5*512; i += stride){
        int j = i & 7, lane = (i >> 3) & 63, t = i >> 9;
        int ks = t % 5, nt = t / 5;
        int cg = nt*16 + (lane & 15);
        int k = ks*32 + ((lane >> 4) << 3) + j;
        float v = 0.f;
        if (cg < H1){
            if (k < 128) v = eW1[(size_t)(128+k)*H1 + cg];
            else if (k < 137) v = eW1[(size_t)(256+(k-128))*H1 + cg];
        }
        W1F[i] = f2bf(v);
    }
    for (int i = i0; i < 34*4*512; i += stride){
        int j = i & 7, lane = (i >> 3) & 63, t = i >> 9;
        int ks = t & 3, nt = t >> 2;
        int cg = nt*16 + (lane & 15);
        int k = ks*32 + ((lane >> 4) << 3) + j;
        float v = (cg < H1) ? eW1[(size_t)k*H1 + cg] : 0.f;
        WPF[i] = f2bf(v);
    }
    for (int i = i0; i < 34*512; i += stride){
        int j = i & 7, lane = (i >> 3) & 63, nt = i >> 9;
        int kl = ((lane >> 4) << 3) + j;       // 0..31, valid < 16
        int col = lane & 15;                   // f (A-row) = output feature
        int row = nt*16 + kl;
        float v = (kl < 16 && row < H1) ? eW2[(size_t)row*MD + col] : 0.f;
        W2F2[i] = f2bf(v);
    }
}

// ---------------- Kernel P: fused topk (blocks 0..2047, LDS-staged coors) + pmat -------------
__global__ __launch_bounds__(256) void prep_kernel(const float* __restrict__ coors,
        const float* __restrict__ feats,
        const unsigned short* __restrict__ WPF, const float* __restrict__ eb1,
        int* __restrict__ idx_ws, float* __restrict__ dv_ws, float* __restrict__ P){
    __shared__ float cs[Nn*3];     // 24576 B, topk branch only
    int bid = blockIdx.x;
    int tid = threadIdx.x;
    if (bid < TOPK_BLKS){
        int w = tid >> 6, lane = tid & 63;
        int node = bid * 4 + w;
        int b = node >> 11;
        const float* cbp = coors + (size_t)b * Nn * 3;
        for (int t = tid; t < Nn*3; t += 256) cs[t] = cbp[t];
        __syncthreads();
        float cx = cs[(node & (Nn-1))*3+0], cy = cs[(node & (Nn-1))*3+1], cz = cs[(node & (Nn-1))*3+2];
        float d[32];
        #pragma unroll
        for (int t = 0; t < 32; t++){
            int j = t*64 + lane;
            float dx = cx - cs[j*3+0], dy = cy - cs[j*3+1], dz = cz - cs[j*3+2];
            d[t] = dx*dx + dy*dy + dz*dz;
        }
        float md = d[0]; int mj = lane;
        #pragma unroll
        for (int t = 1; t < 32; t++){
            int jt = t*64 + lane;
            if (d[t] < md){ md = d[t]; mj = jt; }
        }
        for (int r = 0; r < Kk; r++){
            float bd = md; int bj = mj;
            #pragma unroll
            for (int off = 32; off; off >>= 1){
                float d2 = __shfl_xor(bd, off); int j2 = __shfl_xor(bj, off);
                if (d2 < bd || (d2 == bd && j2 < bj)){ bd = d2; bj = j2; }
            }
            if (lane == 0){
                idx_ws[node*Kk + r] = bj;
                dv_ws[node*Kk + r] = bd;
            }
            if (mj == bj){
                md = 3.4e38f; mj = 0x7fffffff;
                #pragma unroll
                for (int t = 0; t < 32; t++){
                    int jt = t*64 + lane;
                    if (jt == bj) d[t] = 3.4e38f;
                    if (d[t] < md){ md = d[t]; mj = jt; }
                }
            }
        }
    } else {
        int wid = tid >> 6, lane = tid & 63;
        int node0 = (bid - TOPK_BLKS) * 32;
        int kg = (lane >> 4) * 8;
        s16x8 af[2][4];
        #pragma unroll
        for (int m = 0; m < 2; m++){
            const float* fr = feats + (size_t)(node0 + m*16 + (lane & 15)) * DIMd;
            #pragma unroll
            for (int ks = 0; ks < 4; ks++){
                f32x4 lo = *(const f32x4*)(fr + ks*32 + kg);
                f32x4 hi = *(const f32x4*)(fr + ks*32 + kg + 4);
                union { s16x8 v; unsigned u[4]; } pk;
                pk.u[0] = cvt_pk_bf16(lo[0], lo[1]); pk.u[1] = cvt_pk_bf16(lo[2], lo[3]);
                pk.u[2] = cvt_pk_bf16(hi[0], hi[1]); pk.u[3] = cvt_pk_bf16(hi[2], hi[3]);
                af[m][ks] = pk.v;
            }
        }
        const s16x8* WPFv = (const s16x8*)WPF;
        for (int nt = wid; nt < 34; nt += 4){
            f32x4 acc0 = {0,0,0,0}, acc1 = {0,0,0,0};
            #pragma unroll
            for (int ks = 0; ks < 4; ks++){
                s16x8 bb = WPFv[(nt*4 + ks)*64 + lane];
                acc0 = __builtin_amdgcn_mfma_f32_16x16x32_bf16(af[0][ks], bb, acc0, 0, 0, 0);
                acc1 = __builtin_amdgcn_mfma_f32_16x16x32_bf16(af[1][ks], bb, acc1, 0, 0, 0);
            }
            int cg = nt*16 + (lane & 15);
            if (cg < H1){
                float b = eb1[cg];
                int r0 = (lane >> 4) * 4;
                #pragma unroll
                for (int r = 0; r < 4; r++){
                    P[(size_t)(node0 + r0 + r)*PW2 + cg]      = acc0[r] + b;
                    P[(size_t)(node0 + 16 + r0 + r)*PW2 + cg] = acc1[r] + b;
                }
            }
        }
    }
}

// ---------------- Kernel C: edge main loop (r12 shape; (256,7): cap 72 >= ~70 true need) -----
// NOTE register accounting (r13 lesson): CSV VGPR_Count=40 is ARCH regs only; MFMA
// accumulators add ~24-32 acc-regs in the unified file -> total ~70. (256,8) cap=64 spills.
__global__ __launch_bounds__(256, 7) void edge_kernel(
        const float* __restrict__ feats, const float* __restrict__ eb2,
        const float* __restrict__ P, const unsigned short* __restrict__ W1F,
        const unsigned short* __restrict__ W2F2,
        const int* __restrict__ idx_ws, const float* __restrict__ dv_ws,
        float* __restrict__ m_ws){
    __shared__ float Pi_lds[544];                           // 2176 B
    __shared__ __align__(16) unsigned short aenc[Kk][32];   // 2048 B
    __shared__ int js[Kk];
    __shared__ float m_red[4][Kk][MD+1];                    // 8704 B  -> ~13.1 KB

    int node = blockIdx.x; int tid = threadIdx.x;
    int b = node >> 11;
    int wid = tid >> 6, lane = tid & 63;

    const float* Pn = P + (size_t)node*PW2;
    Pi_lds[tid]       = Pn[tid];
    { int c = tid + 256; Pi_lds[c] = (c < PW2) ? Pn[c] : 0.f; }
    if (tid < 32){ int c = 512 + tid; Pi_lds[c] = (c < PW2) ? Pn[c] : 0.f; }
    if (tid < Kk){
        int j = idx_ws[node*Kk + tid];
        float dv = dv_ws[node*Kk + tid];
        js[tid] = j;
        unsigned short e[9];
        e[0] = f2bf(sinf(dv));        e[1] = f2bf(sinf(dv*0.5f));
        e[2] = f2bf(sinf(dv*0.25f));  e[3] = f2bf(sinf(dv*0.125f));
        e[4] = f2bf(cosf(dv));        e[5] = f2bf(cosf(dv*0.5f));
        e[6] = f2bf(cosf(dv*0.25f));  e[7] = f2bf(cosf(dv*0.125f));
        e[8] = f2bf(dv);
        #pragma unroll
        for (int q = 0; q < 9; q++) aenc[tid][q] = e[q];
        #pragma unroll
        for (int q = 9; q < 32; q++) aenc[tid][q] = 0;
    }
    __syncthreads();

    // per-lane fragment of [feats_j | enc] for neighbor = lane&15 (+16 for half 1);
    // used as MFMA *B* operand (col = neighbor) — same per-lane layout as A.
    int kg = (lane >> 4) * 8;
    int grp = lane >> 4, n16 = lane & 15;
    s16x8 af[2][5];
    #pragma unroll
    for (int m = 0; m < 2; m++){
        int row = m*16 + n16;
        int jgl = (b << 11) + js[row];
        const float* fr = feats + (size_t)jgl * DIMd;
        #pragma unroll
        for (int ks = 0; ks < 4; ks++){
            f32x4 lo = *(const f32x4*)(fr + ks*32 + kg);
            f32x4 hi = *(const f32x4*)(fr + ks*32 + kg + 4);
            union { s16x8 v; unsigned u[4]; } pk;
            pk.u[0] = cvt_pk_bf16(lo[0], lo[1]); pk.u[1] = cvt_pk_bf16(lo[2], lo[3]);
            pk.u[2] = cvt_pk_bf16(hi[0], hi[1]); pk.u[3] = cvt_pk_bf16(hi[2], hi[3]);
            af[m][ks] = pk.v;
        }
        af[m][4] = *(const s16x8*)(&aenc[row][kg]);
    }

    int s1 = ((grp & 1) << 1) | (grp >> 1);   // 0,1,2,3 -> 0,2,1,3
    int s2 = s1 ^ 1;
    int addr1 = ((s1 << 4) | n16) << 2;
    int addr2 = ((s2 << 4) | n16) << 2;

    // Fused GEMM1' (C'[cg][n]) + silu + bpermute-transpose + GEMM2 (m^T[f][n])
    const s16x8* W1Fv  = (const s16x8*)W1F;
    const s16x8* W2F2v = (const s16x8*)W2F2;
    f32x4 macc0 = {0,0,0,0}, macc1 = {0,0,0,0};
    for (int nt = wid; nt < 34; nt += 4){
        f32x4 acc0 = {0,0,0,0}, acc1 = {0,0,0,0};
        #pragma unroll
        for (int ks = 0; ks < 5; ks++){
            s16x8 aw = W1Fv[(nt*5 + ks)*64 + lane];     // A: rows = cg tile
            acc0 = __builtin_amdgcn_mfma_f32_16x16x32_bf16(aw, af[0][ks], acc0, 0, 0, 0);
            acc1 = __builtin_amdgcn_mfma_f32_16x16x32_bf16(aw, af[1][ks], acc1, 0, 0, 0);
        }
        s16x8 w2a = W2F2v[nt*64 + lane];                // A: rows = f, k>=16 zeroed
        int cgb = nt*16 + grp*4;
        float x0[4], x1[4];
        #pragma unroll
        for (int r = 0; r < 4; r++){
            float pic = Pi_lds[cgb + r];                // group-uniform broadcast read
            x0[r] = silu_f(acc0[r] + pic);
            x1[r] = silu_f(acc1[r] + pic);
        }
        unsigned p00 = cvt_pk_bf16(x0[0], x0[1]), p01 = cvt_pk_bf16(x0[2], x0[3]);
        unsigned p10 = cvt_pk_bf16(x1[0], x1[1]), p11 = cvt_pk_bf16(x1[2], x1[3]);
        union { s16x8 v; int u[4]; } b0, b1;
        b0.u[0] = __builtin_amdgcn_ds_bpermute(addr1, (int)p00);
        b0.u[1] = __builtin_amdgcn_ds_bpermute(addr1, (int)p01);
        b0.u[2] = __builtin_amdgcn_ds_bpermute(addr2, (int)p00);
        b0.u[3] = __builtin_amdgcn_ds_bpermute(addr2, (int)p01);
        b1.u[0] = __builtin_amdgcn_ds_bpermute(addr1, (int)p10);
        b1.u[1] = __builtin_amdgcn_ds_bpermute(addr1, (int)p11);
        b1.u[2] = __builtin_amdgcn_ds_bpermute(addr2, (int)p10);
        b1.u[3] = __builtin_amdgcn_ds_bpermute(addr2, (int)p11);
        macc0 = __builtin_amdgcn_mfma_f32_16x16x32_bf16(w2a, b0.v, macc0, 0, 0, 0);
        macc1 = __builtin_amdgcn_mfma_f32_16x16x32_bf16(w2a, b1.v, macc1, 0, 0, 0);
    }
    #pragma unroll
    for (int r = 0; r < 4; r++){
        m_red[wid][n16][grp*4 + r]      = macc0[r];
        m_red[wid][16 + n16][grp*4 + r] = macc1[r];
    }
    __syncthreads();
    #pragma unroll
    for (int t = tid; t < Kk*MD; t += 256){
        int n = t >> 4, f = t & 15;
        float s = m_red[0][n][f] + m_red[1][n][f] + m_red[2][n][f] + m_red[3][n][f];
        m_ws[(size_t)node*(Kk*MD) + t] = silu_f(s + eb2[f]);
    }
}

// ---------------- Kernel N: finish (mi, cw MLP, coors) + node MLP, 8 nodes/block -------------
__global__ __launch_bounds__(256) void finish_kernel(const float* __restrict__ feats,
        const float* __restrict__ coors,
        const float* __restrict__ m_ws, const int* __restrict__ idx_ws,
        const float* __restrict__ cW1, const float* __restrict__ cb1,
        const float* __restrict__ cW2, const float* __restrict__ cb2,
        const float* __restrict__ nW1, const float* __restrict__ nb1,
        const float* __restrict__ nW2, const float* __restrict__ nb2,
        float* __restrict__ out, float* __restrict__ coors_out){
    __shared__ float msh[8][Kk][MD+1];   // 17408 B
    __shared__ float insT[NDI][12];      // 6912 B
    __shared__ float hsdT[NDH][12];      // 12288 B
    int tid = threadIdx.x;
    int node0 = blockIdx.x * 8;
    const float* mp = m_ws + (size_t)node0*(Kk*MD);
    for (int t = tid; t < 8*Kk*MD; t += 256)
        msh[t >> 9][(t >> 4) & 31][t & 15] = mp[t];
    for (int t = tid; t < 8*DIMd; t += 256)
        insT[t & 127][t >> 7] = feats[(size_t)node0*DIMd + t];
    int nl = tid >> 5, n = tid & 31;
    int node = node0 + nl;
    int b = node >> 11;
    int j = idx_ws[node*Kk + n];
    int jg = (b << 11) + j;
    float rx = coors[node*3+0] - coors[jg*3+0];
    float ry = coors[node*3+1] - coors[jg*3+1];
    float rz = coors[node*3+2] - coors[jg*3+2];
    __syncthreads();
    if (tid < 128){
        int m = tid >> 4, f = tid & 15;
        float s = 0.f;
        #pragma unroll
        for (int q = 0; q < Kk; q++) s += msh[m][q][f];
        insT[DIMd + f][m] = s;
    }
    float mv[MD];
    #pragma unroll
    for (int f = 0; f < MD; f++) mv[f] = msh[nl][n][f];
    float p = 0.f;
    #pragma unroll 4
    for (int ug = 0; ug < 16; ug++){
        f32x4 a4 = *(const f32x4*)(cb1 + ug*4);
        #pragma unroll
        for (int f = 0; f < MD; f++){
            f32x4 w4 = *(const f32x4*)(cW1 + f*64 + ug*4);
            a4 += (f32x4){mv[f],mv[f],mv[f],mv[f]} * w4;
        }
        f32x4 c4 = *(const f32x4*)(cW2 + ug*4);
        p += silu_f(a4[0])*c4[0] + silu_f(a4[1])*c4[1]
           + silu_f(a4[2])*c4[2] + silu_f(a4[3])*c4[3];
    }
    float cw = p + cb2[0];
    float vx = cw*rx, vy = cw*ry, vz = cw*rz;
    #pragma unroll
    for (int off = 1; off < 32; off <<= 1){
        vx += __shfl_xor(vx, off); vy += __shfl_xor(vy, off); vz += __shfl_xor(vz, off);
    }
    if (n == 0){
        coors_out[node*3+0] = vx + coors[node*3+0];
        coors_out[node*3+1] = vy + coors[node*3+1];
        coors_out[node*3+2] = vz + coors[node*3+2];
    }
    __syncthreads();
    float bias = nb1[tid];
    f32x2 acc[4];
    #pragma unroll
    for (int q = 0; q < 4; q++) acc[q] = (f32x2){bias, bias};
    for (int k = 0; k < NDI; k++){
        float wv = nW1[(size_t)k*NDH + tid];
        f32x2 w2 = {wv, wv};
        acc[0] += *(const f32x2*)&insT[k][0] * w2;
        acc[1] += *(const f32x2*)&insT[k][2] * w2;
        acc[2] += *(const f32x2*)&insT[k][4] * w2;
        acc[3] += *(const f32x2*)&insT[k][6] * w2;
    }
    #pragma unroll
    for (int q = 0; q < 4; q++) *(f32x2*)&hsdT[tid][2*q] = silu2(acc[q]);
    __syncthreads();
    int c = tid & 127, half = tid >> 7;
    float b2 = nb2[c];
    f32x2 a0 = {b2, b2}, a1 = {b2, b2};
    for (int k = 0; k < NDH; k++){
        float wv = nW2[(size_t)k*DIMd + c];
        f32x2 w2 = {wv, wv};
        a0 += *(const f32x2*)&hsdT[k][half*4]     * w2;
        a1 += *(const f32x2*)&hsdT[k][half*4 + 2] * w2;
    }
    #pragma unroll
    for (int q = 0; q < 4; q++){
        int m = half*4 + q;
        float v = (q < 2) ? a0[q & 1] : a1[q & 1];
        out[(size_t)(node0+m)*DIMd + c] = v + feats[(size_t)(node0+m)*DIMd + c];
    }
}

extern "C" void kernel_launch(void* const* d_in, const int* in_sizes, int n_in,
                              void* d_out, int out_size, void* d_ws, size_t ws_size,
                              hipStream_t stream){
    const float* feats = (const float*)d_in[0];
    const float* coors = (const float*)d_in[1];
    const float* eW1 = (const float*)d_in[2];
    const float* eb1 = (const float*)d_in[3];
    const float* eW2 = (const float*)d_in[4];
    const float* eb2 = (const float*)d_in[5];
    const float* cW1 = (const float*)d_in[6];
    const float* cb1 = (const float*)d_in[7];
    const float* cW2 = (const float*)d_in[8];
    const float* cb2 = (const float*)d_in[9];
    const float* nW1 = (const float*)d_in[10];
    const float* nb1 = (const float*)d_in[11];
    const float* nW2 = (const float*)d_in[12];
    const float* nb2 = (const float*)d_in[13];
    float* out = (float*)d_out;                        // node_out: 4*2048*128
    float* coors_out = out + (size_t)Bb*Nn*DIMd;       // coors_out: 4*2048*3

    char* ws = (char*)d_ws;
    size_t off = 0;
    int*   idx_ws = (int*)(ws + off);   off += (1u<<20);          // 1 MB
    float* dv_ws  = (float*)(ws + off); off += (1u<<20);          // 1 MB
    float* Pd     = (float*)(ws + off); off += 17367040u;         // 8192*530*4
    float* m_ws   = (float*)(ws + off); off += 16777216u;         // 8192*512*4
    unsigned short* W1F  = (unsigned short*)(ws + off); off += 174080u;  // 34*5*512*2
    unsigned short* WPF  = (unsigned short*)(ws + off); off += 139264u;  // 34*4*512*2
    unsigned short* W2F2 = (unsigned short*)(ws + off); off += 34816u;   // 34*512*2

    fragw_kernel<<<256, 256, 0, stream>>>(eW1, eW2, W1F, WPF, W2F2);
    prep_kernel<<<TOPK_BLKS + PMAT_BLKS, 256, 0, stream>>>(coors, feats, WPF, eb1,
                                                           idx_ws, dv_ws, Pd);
    edge_kernel<<<Bb*Nn, 256, 0, stream>>>(feats, eb2, Pd, W1F, W2F2,
                                           idx_ws, dv_ws, m_ws);
    finish_kernel<<<Bb*Nn/8, 256, 0, stream>>>(feats, coors, m_ws, idx_ws,
                                               cW1, cb1, cW2, cb2,
                                               nW1, nb1, nW2, nb2, out, coors_out);
}

// Round 15
// 283.912 us; speedup vs baseline: 1.6407x; 1.1526x over previous
//
#include <hip/hip_runtime.h>
#include <hip/hip_bf16.h>
#include <math.h>

#define Bb 4
#define Nn 2048
#define DIMd 128
#define Kk 32
#define H1 530      // EDGE_IN*2
#define PW2 530     // P table width (i-part only)
#define MD 16
#define NDH 256
#define NDI 144
#define TOPK_BLKS (Bb*Nn/4)     // 2048
#define PMAT_BLKS (Bb*Nn/32)    // 256

typedef float f32x2 __attribute__((ext_vector_type(2)));
typedef float f32x4 __attribute__((ext_vector_type(4)));
typedef short s16x8 __attribute__((ext_vector_type(8)));

__device__ __forceinline__ unsigned short f2bf(float f){
    union { float f; unsigned u; } v; v.f = f;
    unsigned r = v.u + 0x7FFFu + ((v.u >> 16) & 1u);
    return (unsigned short)(r >> 16);
}
__device__ __forceinline__ float silu_f(float x){
    float e = __builtin_amdgcn_exp2f(x * -1.442695041f);
    return x * __builtin_amdgcn_rcpf(1.0f + e);
}
__device__ __forceinline__ f32x2 silu2(f32x2 x){
    float e0 = __builtin_amdgcn_exp2f(x[0] * -1.442695041f);
    float e1 = __builtin_amdgcn_exp2f(x[1] * -1.442695041f);
    f32x2 r;
    r[0] = x[0] * __builtin_amdgcn_rcpf(1.0f + e0);
    r[1] = x[1] * __builtin_amdgcn_rcpf(1.0f + e1);
    return r;
}
__device__ __forceinline__ unsigned cvt_pk_bf16(float a, float b){
    unsigned r;
    asm("v_cvt_pk_bf16_f32 %0, %1, %2" : "=v"(r) : "v"(a), "v"(b));
    return r;
}

// ---------------- Kernel F: build all MFMA fragments (bf16, fragment-linear) -----------------
__global__ __launch_bounds__(256) void fragw_kernel(const float* __restrict__ eW1,
        const float* __restrict__ eW2,
        unsigned short* __restrict__ W1F, unsigned short* __restrict__ WPF,
        unsigned short* __restrict__ W2F2){
    int i0 = blockIdx.x * 256 + threadIdx.x;
    int stride = gridDim.x * 256;
    for (int i = i0; i < 34*5*512; i += stride){
        int j = i & 7, lane = (i >> 3) & 63, t = i >> 9;
        int ks = t % 5, nt = t / 5;
        int cg = nt*16 + (lane & 15);
        int k = ks*32 + ((lane >> 4) << 3) + j;
        float v = 0.f;
        if (cg < H1){
            if (k < 128) v = eW1[(size_t)(128+k)*H1 + cg];
            else if (k < 137) v = eW1[(size_t)(256+(k-128))*H1 + cg];
        }
        W1F[i] = f2bf(v);
    }
    for (int i = i0; i < 34*4*512; i += stride){
        int j = i & 7, lane = (i >> 3) & 63, t = i >> 9;
        int ks = t & 3, nt = t >> 2;
        int cg = nt*16 + (lane & 15);
        int k = ks*32 + ((lane >> 4) << 3) + j;
        float v = (cg < H1) ? eW1[(size_t)k*H1 + cg] : 0.f;
        WPF[i] = f2bf(v);
    }
    for (int i = i0; i < 34*512; i += stride){
        int j = i & 7, lane = (i >> 3) & 63, nt = i >> 9;
        int kl = ((lane >> 4) << 3) + j;       // 0..31, valid < 16
        int col = lane & 15;                   // f (A-row) = output feature
        int row = nt*16 + kl;
        float v = (kl < 16 && row < H1) ? eW2[(size_t)row*MD + col] : 0.f;
        W2F2[i] = f2bf(v);
    }
}

// ---------------- Kernel P: fused topk (blocks 0..2047, LDS-staged coors) + pmat -------------
__global__ __launch_bounds__(256) void prep_kernel(const float* __restrict__ coors,
        const float* __restrict__ feats,
        const unsigned short* __restrict__ WPF, const float* __restrict__ eb1,
        int* __restrict__ idx_ws, float* __restrict__ dv_ws, float* __restrict__ P){
    __shared__ float cs[Nn*3];     // 24576 B, topk branch only
    int bid = blockIdx.x;
    int tid = threadIdx.x;
    if (bid < TOPK_BLKS){
        int w = tid >> 6, lane = tid & 63;
        int node = bid * 4 + w;
        int b = node >> 11;
        const float* cbp = coors + (size_t)b * Nn * 3;
        for (int t = tid; t < Nn*3; t += 256) cs[t] = cbp[t];
        __syncthreads();
        float cx = cs[(node & (Nn-1))*3+0], cy = cs[(node & (Nn-1))*3+1], cz = cs[(node & (Nn-1))*3+2];
        float d[32];
        #pragma unroll
        for (int t = 0; t < 32; t++){
            int j = t*64 + lane;
            float dx = cx - cs[j*3+0], dy = cy - cs[j*3+1], dz = cz - cs[j*3+2];
            d[t] = dx*dx + dy*dy + dz*dz;
        }
        float md = d[0]; int mj = lane;
        #pragma unroll
        for (int t = 1; t < 32; t++){
            int jt = t*64 + lane;
            if (d[t] < md){ md = d[t]; mj = jt; }
        }
        for (int r = 0; r < Kk; r++){
            float bd = md; int bj = mj;
            #pragma unroll
            for (int off = 32; off; off >>= 1){
                float d2 = __shfl_xor(bd, off); int j2 = __shfl_xor(bj, off);
                if (d2 < bd || (d2 == bd && j2 < bj)){ bd = d2; bj = j2; }
            }
            if (lane == 0){
                idx_ws[node*Kk + r] = bj;
                dv_ws[node*Kk + r] = bd;
            }
            if (mj == bj){
                md = 3.4e38f; mj = 0x7fffffff;
                #pragma unroll
                for (int t = 0; t < 32; t++){
                    int jt = t*64 + lane;
                    if (jt == bj) d[t] = 3.4e38f;
                    if (d[t] < md){ md = d[t]; mj = jt; }
                }
            }
        }
    } else {
        int wid = tid >> 6, lane = tid & 63;
        int node0 = (bid - TOPK_BLKS) * 32;
        int kg = (lane >> 4) * 8;
        s16x8 af[2][4];
        #pragma unroll
        for (int m = 0; m < 2; m++){
            const float* fr = feats + (size_t)(node0 + m*16 + (lane & 15)) * DIMd;
            #pragma unroll
            for (int ks = 0; ks < 4; ks++){
                f32x4 lo = *(const f32x4*)(fr + ks*32 + kg);
                f32x4 hi = *(const f32x4*)(fr + ks*32 + kg + 4);
                union { s16x8 v; unsigned u[4]; } pk;
                pk.u[0] = cvt_pk_bf16(lo[0], lo[1]); pk.u[1] = cvt_pk_bf16(lo[2], lo[3]);
                pk.u[2] = cvt_pk_bf16(hi[0], hi[1]); pk.u[3] = cvt_pk_bf16(hi[2], hi[3]);
                af[m][ks] = pk.v;
            }
        }
        const s16x8* WPFv = (const s16x8*)WPF;
        for (int nt = wid; nt < 34; nt += 4){
            f32x4 acc0 = {0,0,0,0}, acc1 = {0,0,0,0};
            #pragma unroll
            for (int ks = 0; ks < 4; ks++){
                s16x8 bb = WPFv[(nt*4 + ks)*64 + lane];
                acc0 = __builtin_amdgcn_mfma_f32_16x16x32_bf16(af[0][ks], bb, acc0, 0, 0, 0);
                acc1 = __builtin_amdgcn_mfma_f32_16x16x32_bf16(af[1][ks], bb, acc1, 0, 0, 0);
            }
            int cg = nt*16 + (lane & 15);
            if (cg < H1){
                float b = eb1[cg];
                int r0 = (lane >> 4) * 4;
                #pragma unroll
                for (int r = 0; r < 4; r++){
                    P[(size_t)(node0 + r0 + r)*PW2 + cg]      = acc0[r] + b;
                    P[(size_t)(node0 + 16 + r0 + r)*PW2 + cg] = acc1[r] + b;
                }
            }
        }
    }
}

// ---------------- Kernel C: edge main loop (r10 shape, (256,6), unroll-2 nt loop) ------------
__global__ __launch_bounds__(256, 6) void edge_kernel(
        const float* __restrict__ feats, const float* __restrict__ eb2,
        const float* __restrict__ P, const unsigned short* __restrict__ W1F,
        const unsigned short* __restrict__ W2F2,
        const int* __restrict__ idx_ws, const float* __restrict__ dv_ws,
        float* __restrict__ m_ws){
    __shared__ float Pi_lds[544];                           // 2176 B
    __shared__ __align__(16) unsigned short aenc[Kk][32];   // 2048 B
    __shared__ int js[Kk];
    __shared__ float m_red[4][Kk][MD+1];                    // 8704 B  -> ~13.1 KB

    int node = blockIdx.x; int tid = threadIdx.x;
    int b = node >> 11;
    int wid = tid >> 6, lane = tid & 63;

    const float* Pn = P + (size_t)node*PW2;
    Pi_lds[tid]       = Pn[tid];
    { int c = tid + 256; Pi_lds[c] = (c < PW2) ? Pn[c] : 0.f; }
    if (tid < 32){ int c = 512 + tid; Pi_lds[c] = (c < PW2) ? Pn[c] : 0.f; }
    if (tid < Kk){
        int j = idx_ws[node*Kk + tid];
        float dv = dv_ws[node*Kk + tid];
        js[tid] = j;
        unsigned short e[9];
        e[0] = f2bf(sinf(dv));        e[1] = f2bf(sinf(dv*0.5f));
        e[2] = f2bf(sinf(dv*0.25f));  e[3] = f2bf(sinf(dv*0.125f));
        e[4] = f2bf(cosf(dv));        e[5] = f2bf(cosf(dv*0.5f));
        e[6] = f2bf(cosf(dv*0.25f));  e[7] = f2bf(cosf(dv*0.125f));
        e[8] = f2bf(dv);
        #pragma unroll
        for (int q = 0; q < 9; q++) aenc[tid][q] = e[q];
        #pragma unroll
        for (int q = 9; q < 32; q++) aenc[tid][q] = 0;
    }
    __syncthreads();

    // per-lane fragment of [feats_j | enc] for neighbor = lane&15 (+16 for half 1);
    // used as MFMA *B* operand (col = neighbor) — same per-lane layout as A.
    int kg = (lane >> 4) * 8;
    int grp = lane >> 4, n16 = lane & 15;
    s16x8 af[2][5];
    #pragma unroll
    for (int m = 0; m < 2; m++){
        int row = m*16 + n16;
        int jgl = (b << 11) + js[row];
        const float* fr = feats + (size_t)jgl * DIMd;
        #pragma unroll
        for (int ks = 0; ks < 4; ks++){
            f32x4 lo = *(const f32x4*)(fr + ks*32 + kg);
            f32x4 hi = *(const f32x4*)(fr + ks*32 + kg + 4);
            union { s16x8 v; unsigned u[4]; } pk;
            pk.u[0] = cvt_pk_bf16(lo[0], lo[1]); pk.u[1] = cvt_pk_bf16(lo[2], lo[3]);
            pk.u[2] = cvt_pk_bf16(hi[0], hi[1]); pk.u[3] = cvt_pk_bf16(hi[2], hi[3]);
            af[m][ks] = pk.v;
        }
        af[m][4] = *(const s16x8*)(&aenc[row][kg]);
    }

    // bpermute source lanes (r10 wrapped form — remap was neutral on conflicts, cheaper regs)
    int addr1 = ((((2*grp)    ) << 4) | n16) << 2;
    int addr2 = ((((2*grp) + 1) << 4) | n16) << 2;

    // Fused GEMM1' (C'[cg][n]) + silu + bpermute-transpose + GEMM2 (m^T[f][n])
    const s16x8* W1Fv  = (const s16x8*)W1F;
    const s16x8* W2F2v = (const s16x8*)W2F2;
    f32x4 macc0 = {0,0,0,0}, macc1 = {0,0,0,0};
    #pragma unroll 2
    for (int nt = wid; nt < 34; nt += 4){
        f32x4 acc0 = {0,0,0,0}, acc1 = {0,0,0,0};
        #pragma unroll
        for (int ks = 0; ks < 5; ks++){
            s16x8 aw = W1Fv[(nt*5 + ks)*64 + lane];     // A: rows = cg tile
            acc0 = __builtin_amdgcn_mfma_f32_16x16x32_bf16(aw, af[0][ks], acc0, 0, 0, 0);
            acc1 = __builtin_amdgcn_mfma_f32_16x16x32_bf16(aw, af[1][ks], acc1, 0, 0, 0);
        }
        s16x8 w2a = W2F2v[nt*64 + lane];                // A: rows = f, k>=16 zeroed
        int cgb = nt*16 + grp*4;
        float x0[4], x1[4];
        #pragma unroll
        for (int r = 0; r < 4; r++){
            float pic = Pi_lds[cgb + r];                // group-uniform broadcast read
            x0[r] = silu_f(acc0[r] + pic);
            x1[r] = silu_f(acc1[r] + pic);
        }
        unsigned p00 = cvt_pk_bf16(x0[0], x0[1]), p01 = cvt_pk_bf16(x0[2], x0[3]);
        unsigned p10 = cvt_pk_bf16(x1[0], x1[1]), p11 = cvt_pk_bf16(x1[2], x1[3]);
        union { s16x8 v; int u[4]; } b0, b1;
        b0.u[0] = __builtin_amdgcn_ds_bpermute(addr1, (int)p00);
        b0.u[1] = __builtin_amdgcn_ds_bpermute(addr1, (int)p01);
        b0.u[2] = __builtin_amdgcn_ds_bpermute(addr2, (int)p00);
        b0.u[3] = __builtin_amdgcn_ds_bpermute(addr2, (int)p01);
        b1.u[0] = __builtin_amdgcn_ds_bpermute(addr1, (int)p10);
        b1.u[1] = __builtin_amdgcn_ds_bpermute(addr1, (int)p11);
        b1.u[2] = __builtin_amdgcn_ds_bpermute(addr2, (int)p10);
        b1.u[3] = __builtin_amdgcn_ds_bpermute(addr2, (int)p11);
        macc0 = __builtin_amdgcn_mfma_f32_16x16x32_bf16(w2a, b0.v, macc0, 0, 0, 0);
        macc1 = __builtin_amdgcn_mfma_f32_16x16x32_bf16(w2a, b1.v, macc1, 0, 0, 0);
    }
    #pragma unroll
    for (int r = 0; r < 4; r++){
        m_red[wid][n16][grp*4 + r]      = macc0[r];
        m_red[wid][16 + n16][grp*4 + r] = macc1[r];
    }
    __syncthreads();
    #pragma unroll
    for (int t = tid; t < Kk*MD; t += 256){
        int n = t >> 4, f = t & 15;
        float s = m_red[0][n][f] + m_red[1][n][f] + m_red[2][n][f] + m_red[3][n][f];
        m_ws[(size_t)node*(Kk*MD) + t] = silu_f(s + eb2[f]);
    }
}

// ---------------- Kernel N: finish (mi, cw MLP, coors) + node MLP, 8 nodes/block -------------
__global__ __launch_bounds__(256) void finish_kernel(const float* __restrict__ feats,
        const float* __restrict__ coors,
        const float* __restrict__ m_ws, const int* __restrict__ idx_ws,
        const float* __restrict__ cW1, const float* __restrict__ cb1,
        const float* __restrict__ cW2, const float* __restrict__ cb2,
        const float* __restrict__ nW1, const float* __restrict__ nb1,
        const float* __restrict__ nW2, const float* __restrict__ nb2,
        float* __restrict__ out, float* __restrict__ coors_out){
    __shared__ float msh[8][Kk][MD+1];   // 17408 B
    __shared__ float insT[NDI][12];      // 6912 B
    __shared__ float hsdT[NDH][12];      // 12288 B
    int tid = threadIdx.x;
    int node0 = blockIdx.x * 8;
    const float* mp = m_ws + (size_t)node0*(Kk*MD);
    for (int t = tid; t < 8*Kk*MD; t += 256)
        msh[t >> 9][(t >> 4) & 31][t & 15] = mp[t];
    for (int t = tid; t < 8*DIMd; t += 256)
        insT[t & 127][t >> 7] = feats[(size_t)node0*DIMd + t];
    int nl = tid >> 5, n = tid & 31;
    int node = node0 + nl;
    int b = node >> 11;
    int j = idx_ws[node*Kk + n];
    int jg = (b << 11) + j;
    float rx = coors[node*3+0] - coors[jg*3+0];
    float ry = coors[node*3+1] - coors[jg*3+1];
    float rz = coors[node*3+2] - coors[jg*3+2];
    __syncthreads();
    if (tid < 128){
        int m = tid >> 4, f = tid & 15;
        float s = 0.f;
        #pragma unroll
        for (int q = 0; q < Kk; q++) s += msh[m][q][f];
        insT[DIMd + f][m] = s;
    }
    float mv[MD];
    #pragma unroll
    for (int f = 0; f < MD; f++) mv[f] = msh[nl][n][f];
    float p = 0.f;
    #pragma unroll 4
    for (int ug = 0; ug < 16; ug++){
        f32x4 a4 = *(const f32x4*)(cb1 + ug*4);
        #pragma unroll
        for (int f = 0; f < MD; f++){
            f32x4 w4 = *(const f32x4*)(cW1 + f*64 + ug*4);
            a4 += (f32x4){mv[f],mv[f],mv[f],mv[f]} * w4;
        }
        f32x4 c4 = *(const f32x4*)(cW2 + ug*4);
        p += silu_f(a4[0])*c4[0] + silu_f(a4[1])*c4[1]
           + silu_f(a4[2])*c4[2] + silu_f(a4[3])*c4[3];
    }
    float cw = p + cb2[0];
    float vx = cw*rx, vy = cw*ry, vz = cw*rz;
    #pragma unroll
    for (int off = 1; off < 32; off <<= 1){
        vx += __shfl_xor(vx, off); vy += __shfl_xor(vy, off); vz += __shfl_xor(vz, off);
    }
    if (n == 0){
        coors_out[node*3+0] = vx + coors[node*3+0];
        coors_out[node*3+1] = vy + coors[node*3+1];
        coors_out[node*3+2] = vz + coors[node*3+2];
    }
    __syncthreads();
    float bias = nb1[tid];
    f32x2 acc[4];
    #pragma unroll
    for (int q = 0; q < 4; q++) acc[q] = (f32x2){bias, bias};
    for (int k = 0; k < NDI; k++){
        float wv = nW1[(size_t)k*NDH + tid];
        f32x2 w2 = {wv, wv};
        acc[0] += *(const f32x2*)&insT[k][0] * w2;
        acc[1] += *(const f32x2*)&insT[k][2] * w2;
        acc[2] += *(const f32x2*)&insT[k][4] * w2;
        acc[3] += *(const f32x2*)&insT[k][6] * w2;
    }
    #pragma unroll
    for (int q = 0; q < 4; q++) *(f32x2*)&hsdT[tid][2*q] = silu2(acc[q]);
    __syncthreads();
    int c = tid & 127, half = tid >> 7;
    float b2 = nb2[c];
    f32x2 a0 = {b2, b2}, a1 = {b2, b2};
    for (int k = 0; k < NDH; k++){
        float wv = nW2[(size_t)k*DIMd + c];
        f32x2 w2 = {wv, wv};
        a0 += *(const f32x2*)&hsdT[k][half*4]     * w2;
        a1 += *(const f32x2*)&hsdT[k][half*4 + 2] * w2;
    }
    #pragma unroll
    for (int q = 0; q < 4; q++){
        int m = half*4 + q;
        float v = (q < 2) ? a0[q & 1] : a1[q & 1];
        out[(size_t)(node0+m)*DIMd + c] = v + feats[(size_t)(node0+m)*DIMd + c];
    }
}

extern "C" void kernel_launch(void* const* d_in, const int* in_sizes, int n_in,
                              void* d_out, int out_size, void* d_ws, size_t ws_size,
                              hipStream_t stream){
    const float* feats = (const float*)d_in[0];
    const float* coors = (const float*)d_in[1];
    const float* eW1 = (const float*)d_in[2];
    const float* eb1 = (const float*)d_in[3];
    const float* eW2 = (const float*)d_in[4];
    const float* eb2 = (const float*)d_in[5];
    const float* cW1 = (const float*)d_in[6];
    const float* cb1 = (const float*)d_in[7];
    const float* cW2 = (const float*)d_in[8];
    const float* cb2 = (const float*)d_in[9];
    const float* nW1 = (const float*)d_in[10];
    const float* nb1 = (const float*)d_in[11];
    const float* nW2 = (const float*)d_in[12];
    const float* nb2 = (const float*)d_in[13];
    float* out = (float*)d_out;                        // node_out: 4*2048*128
    float* coors_out = out + (size_t)Bb*Nn*DIMd;       // coors_out: 4*2048*3

    char* ws = (char*)d_ws;
    size_t off = 0;
    int*   idx_ws = (int*)(ws + off);   off += (1u<<20);          // 1 MB
    float* dv_ws  = (float*)(ws + off); off += (1u<<20);          // 1 MB
    float* Pd     = (float*)(ws + off); off += 17367040u;         // 8192*530*4
    float* m_ws   = (float*)(ws + off); off += 16777216u;         // 8192*512*4
    unsigned short* W1F  = (unsigned short*)(ws + off); off += 174080u;  // 34*5*512*2
    unsigned short* WPF  = (unsigned short*)(ws + off); off += 139264u;  // 34*4*512*2
    unsigned short* W2F2 = (unsigned short*)(ws + off); off += 34816u;   // 34*512*2

    fragw_kernel<<<256, 256, 0, stream>>>(eW1, eW2, W1F, WPF, W2F2);
    prep_kernel<<<TOPK_BLKS + PMAT_BLKS, 256, 0, stream>>>(coors, feats, WPF, eb1,
                                                           idx_ws, dv_ws, Pd);
    edge_kernel<<<Bb*Nn, 256, 0, stream>>>(feats, eb2, Pd, W1F, W2F2,
                                           idx_ws, dv_ws, m_ws);
    finish_kernel<<<Bb*Nn/8, 256, 0, stream>>>(feats, coors, m_ws, idx_ws,
                                               cW1, cb1, cW2, cb2,
                                               nW1, nb1, nW2, nb2, out, coors_out);
}

// Round 18
// 268.821 us; speedup vs baseline: 1.7328x; 1.0561x over previous
//
#include <hip/hip_runtime.h>
#include <hip/hip_bf16.h>
#include <hip/hip_fp8.h>
#include <math.h>

#define Bb 4
#define Nn 2048
#define DIMd 128
#define Kk 32
#define H1 530      // EDGE_IN*2
#define PW2 530     // P table width (i-part only)
#define MD 16
#define NDH 256
#define NDI 144
#define TOPK_BLKS (Bb*Nn/4)     // 2048
#define PMAT_BLKS (Bb*Nn/32)    // 256

typedef float f32x2 __attribute__((ext_vector_type(2)));
typedef float f32x4 __attribute__((ext_vector_type(4)));
typedef short s16x8 __attribute__((ext_vector_type(8)));

__device__ __forceinline__ unsigned short f2bf(float f){
    union { float f; unsigned u; } v; v.f = f;
    unsigned r = v.u + 0x7FFFu + ((v.u >> 16) & 1u);
    return (unsigned short)(r >> 16);
}
__device__ __forceinline__ unsigned char f2fp8(float x){
    __hip_fp8_e4m3 q(x);
    return (unsigned char)q.__x;
}
__device__ __forceinline__ float silu_f(float x){
    float e = __builtin_amdgcn_exp2f(x * -1.442695041f);
    return x * __builtin_amdgcn_rcpf(1.0f + e);
}
__device__ __forceinline__ f32x2 silu2(f32x2 x){
    float e0 = __builtin_amdgcn_exp2f(x[0] * -1.442695041f);
    float e1 = __builtin_amdgcn_exp2f(x[1] * -1.442695041f);
    f32x2 r;
    r[0] = x[0] * __builtin_amdgcn_rcpf(1.0f + e0);
    r[1] = x[1] * __builtin_amdgcn_rcpf(1.0f + e1);
    return r;
}
__device__ __forceinline__ unsigned cvt_pk_bf16(float a, float b){
    unsigned r;
    asm("v_cvt_pk_bf16_f32 %0, %1, %2" : "=v"(r) : "v"(a), "v"(b));
    return r;
}

// ---------------- Kernel F: build MFMA fragments ---------------------------------------------
// W1F8: fp8 e4m3, weights ×256 (raw ~1e-3 is below e4m3 min-normal 2^-6; descale in epilogue)
// WPF : bf16 (pmat B);  W2F2: bf16 (GEMM2)
__global__ __launch_bounds__(256) void fragw_kernel(const float* __restrict__ eW1,
        const float* __restrict__ eW2,
        unsigned char* __restrict__ W1F8, unsigned short* __restrict__ WPF,
        unsigned short* __restrict__ W2F2){
    int i0 = blockIdx.x * 256 + threadIdx.x;
    int stride = gridDim.x * 256;
    for (int i = i0; i < 34*5*512; i += stride){
        int j = i & 7, lane = (i >> 3) & 63, t = i >> 9;
        int ks = t % 5, nt = t / 5;
        int cg = nt*16 + (lane & 15);
        int k = ks*32 + ((lane >> 4) << 3) + j;
        float v = 0.f;
        if (cg < H1){
            if (k < 128) v = eW1[(size_t)(128+k)*H1 + cg];
            else if (k < 137) v = eW1[(size_t)(256+(k-128))*H1 + cg];
        }
        W1F8[i] = f2fp8(v * 256.0f);
    }
    for (int i = i0; i < 34*4*512; i += stride){
        int j = i & 7, lane = (i >> 3) & 63, t = i >> 9;
        int ks = t & 3, nt = t >> 2;
        int cg = nt*16 + (lane & 15);
        int k = ks*32 + ((lane >> 4) << 3) + j;
        float v = (cg < H1) ? eW1[(size_t)k*H1 + cg] : 0.f;
        WPF[i] = f2bf(v);
    }
    for (int i = i0; i < 34*512; i += stride){
        int j = i & 7, lane = (i >> 3) & 63, nt = i >> 9;
        int kl = ((lane >> 4) << 3) + j;       // 0..31, valid < 16
        int col = lane & 15;                   // f (A-row) = output feature
        int row = nt*16 + kl;
        float v = (kl < 16 && row < H1) ? eW2[(size_t)row*MD + col] : 0.f;
        W2F2[i] = f2bf(v);
    }
}

// ---------------- Kernel P: fused topk (blocks 0..2047, LDS-staged coors) + pmat -------------
__global__ __launch_bounds__(256) void prep_kernel(const float* __restrict__ coors,
        const float* __restrict__ feats,
        const unsigned short* __restrict__ WPF, const float* __restrict__ eb1,
        int* __restrict__ idx_ws, float* __restrict__ dv_ws, float* __restrict__ P){
    __shared__ float cs[Nn*3];     // 24576 B, topk branch only
    int bid = blockIdx.x;
    int tid = threadIdx.x;
    if (bid < TOPK_BLKS){
        int w = tid >> 6, lane = tid & 63;
        int node = bid * 4 + w;
        int b = node >> 11;
        const float* cbp = coors + (size_t)b * Nn * 3;
        for (int t = tid; t < Nn*3; t += 256) cs[t] = cbp[t];
        __syncthreads();
        float cx = cs[(node & (Nn-1))*3+0], cy = cs[(node & (Nn-1))*3+1], cz = cs[(node & (Nn-1))*3+2];
        float d[32];
        #pragma unroll
        for (int t = 0; t < 32; t++){
            int j = t*64 + lane;
            float dx = cx - cs[j*3+0], dy = cy - cs[j*3+1], dz = cz - cs[j*3+2];
            d[t] = dx*dx + dy*dy + dz*dz;
        }
        float md = d[0]; int mj = lane;
        #pragma unroll
        for (int t = 1; t < 32; t++){
            int jt = t*64 + lane;
            if (d[t] < md){ md = d[t]; mj = jt; }
        }
        for (int r = 0; r < Kk; r++){
            float bd = md; int bj = mj;
            #pragma unroll
            for (int off = 32; off; off >>= 1){
                float d2 = __shfl_xor(bd, off); int j2 = __shfl_xor(bj, off);
                if (d2 < bd || (d2 == bd && j2 < bj)){ bd = d2; bj = j2; }
            }
            if (lane == 0){
                idx_ws[node*Kk + r] = bj;
                dv_ws[node*Kk + r] = bd;
            }
            if (mj == bj){
                md = 3.4e38f; mj = 0x7fffffff;
                #pragma unroll
                for (int t = 0; t < 32; t++){
                    int jt = t*64 + lane;
                    if (jt == bj) d[t] = 3.4e38f;
                    if (d[t] < md){ md = d[t]; mj = jt; }
                }
            }
        }
    } else {
        int wid = tid >> 6, lane = tid & 63;
        int node0 = (bid - TOPK_BLKS) * 32;
        int kg = (lane >> 4) * 8;
        s16x8 af[2][4];
        #pragma unroll
        for (int m = 0; m < 2; m++){
            const float* fr = feats + (size_t)(node0 + m*16 + (lane & 15)) * DIMd;
            #pragma unroll
            for (int ks = 0; ks < 4; ks++){
                f32x4 lo = *(const f32x4*)(fr + ks*32 + kg);
                f32x4 hi = *(const f32x4*)(fr + ks*32 + kg + 4);
                union { s16x8 v; unsigned u[4]; } pk;
                pk.u[0] = cvt_pk_bf16(lo[0], lo[1]); pk.u[1] = cvt_pk_bf16(lo[2], lo[3]);
                pk.u[2] = cvt_pk_bf16(hi[0], hi[1]); pk.u[3] = cvt_pk_bf16(hi[2], hi[3]);
                af[m][ks] = pk.v;
            }
        }
        const s16x8* WPFv = (const s16x8*)WPF;
        for (int nt = wid; nt < 34; nt += 4){
            f32x4 acc0 = {0,0,0,0}, acc1 = {0,0,0,0};
            #pragma unroll
            for (int ks = 0; ks < 4; ks++){
                s16x8 bb = WPFv[(nt*4 + ks)*64 + lane];
                acc0 = __builtin_amdgcn_mfma_f32_16x16x32_bf16(af[0][ks], bb, acc0, 0, 0, 0);
                acc1 = __builtin_amdgcn_mfma_f32_16x16x32_bf16(af[1][ks], bb, acc1, 0, 0, 0);
            }
            int cg = nt*16 + (lane & 15);
            if (cg < H1){
                float b = eb1[cg];
                int r0 = (lane >> 4) * 4;
                #pragma unroll
                for (int r = 0; r < 4; r++){
                    P[(size_t)(node0 + r0 + r)*PW2 + cg]      = acc0[r] + b;
                    P[(size_t)(node0 + 16 + r0 + r)*PW2 + cg] = acc1[r] + b;
                }
            }
        }
    }
}

// ---------------- Kernel C: edge main loop — GEMM1 in fp8 (half the W1F stream) --------------
__global__ __launch_bounds__(256, 6) void edge_kernel(
        const float* __restrict__ feats, const float* __restrict__ eb2,
        const float* __restrict__ P, const unsigned char* __restrict__ W1F8,
        const unsigned short* __restrict__ W2F2,
        const int* __restrict__ idx_ws, const float* __restrict__ dv_ws,
        float* __restrict__ m_ws){
    __shared__ float Pi_lds[544];                             // 2176 B
    __shared__ __align__(8) unsigned char aenc[Kk][32];       // 1024 B (fp8)
    __shared__ int js[Kk];
    __shared__ float m_red[4][Kk][MD+1];                      // 8704 B

    int node = blockIdx.x; int tid = threadIdx.x;
    int b = node >> 11;
    int wid = tid >> 6, lane = tid & 63;

    const float* Pn = P + (size_t)node*PW2;
    Pi_lds[tid]       = Pn[tid];
    { int c = tid + 256; Pi_lds[c] = (c < PW2) ? Pn[c] : 0.f; }
    if (tid < 32){ int c = 512 + tid; Pi_lds[c] = (c < PW2) ? Pn[c] : 0.f; }
    if (tid < Kk){
        int j = idx_ws[node*Kk + tid];
        float dv = dv_ws[node*Kk + tid];
        js[tid] = j;
        aenc[tid][0] = f2fp8(sinf(dv));        aenc[tid][1] = f2fp8(sinf(dv*0.5f));
        aenc[tid][2] = f2fp8(sinf(dv*0.25f));  aenc[tid][3] = f2fp8(sinf(dv*0.125f));
        aenc[tid][4] = f2fp8(cosf(dv));        aenc[tid][5] = f2fp8(cosf(dv*0.5f));
        aenc[tid][6] = f2fp8(cosf(dv*0.25f));  aenc[tid][7] = f2fp8(cosf(dv*0.125f));
        aenc[tid][8] = f2fp8(dv);
        #pragma unroll
        for (int q = 9; q < 32; q++) aenc[tid][q] = 0;
    }
    __syncthreads();

    // per-lane fp8 fragment of [feats_j | enc] for neighbor = lane&15 (+16 for half 1);
    // used as MFMA *B* operand (col = neighbor).
    int kg = (lane >> 4) * 8;
    int grp = lane >> 4, n16 = lane & 15;
    long af[2][5];
    #pragma unroll
    for (int m = 0; m < 2; m++){
        int row = m*16 + n16;
        int jgl = (b << 11) + js[row];
        const float* fr = feats + (size_t)jgl * DIMd;
        #pragma unroll
        for (int ks = 0; ks < 4; ks++){
            f32x4 lo = *(const f32x4*)(fr + ks*32 + kg);
            f32x4 hi = *(const f32x4*)(fr + ks*32 + kg + 4);
            union { long l; unsigned char c[8]; } pk;
            pk.c[0] = f2fp8(lo[0]); pk.c[1] = f2fp8(lo[1]);
            pk.c[2] = f2fp8(lo[2]); pk.c[3] = f2fp8(lo[3]);
            pk.c[4] = f2fp8(hi[0]); pk.c[5] = f2fp8(hi[1]);
            pk.c[6] = f2fp8(hi[2]); pk.c[7] = f2fp8(hi[3]);
            af[m][ks] = pk.l;
        }
        af[m][4] = *(const long*)(&aenc[row][kg]);
    }

    // bpermute source lanes (wrapped form; grp>=2 dest values multiply zero W2F2 rows)
    int addr1 = ((((2*grp)    ) << 4) | n16) << 2;
    int addr2 = ((((2*grp) + 1) << 4) | n16) << 2;

    // Fused GEMM1' fp8 (C'[cg][n], weights ×256) + descale + Pi + silu
    //   + bpermute-transpose + GEMM2 bf16 (m^T[f][n])
    const long*  W1Fv  = (const long*)W1F8;
    const s16x8* W2F2v = (const s16x8*)W2F2;
    f32x4 macc0 = {0,0,0,0}, macc1 = {0,0,0,0};
    #pragma unroll 2
    for (int nt = wid; nt < 34; nt += 4){
        f32x4 acc0 = {0,0,0,0}, acc1 = {0,0,0,0};
        #pragma unroll
        for (int ks = 0; ks < 5; ks++){
            long aw = W1Fv[(nt*5 + ks)*64 + lane];     // A: rows = cg tile (fp8, ×256)
            acc0 = __builtin_amdgcn_mfma_f32_16x16x32_fp8_fp8(aw, af[0][ks], acc0, 0, 0, 0);
            acc1 = __builtin_amdgcn_mfma_f32_16x16x32_fp8_fp8(aw, af[1][ks], acc1, 0, 0, 0);
        }
        s16x8 w2a = W2F2v[nt*64 + lane];               // A: rows = f, k>=16 zeroed
        int cgb = nt*16 + grp*4;
        float x0[4], x1[4];
        #pragma unroll
        for (int r = 0; r < 4; r++){
            float pic = Pi_lds[cgb + r];               // group-uniform broadcast read
            x0[r] = silu_f(acc0[r]*0.00390625f + pic); // descale 2^-8 (exact)
            x1[r] = silu_f(acc1[r]*0.00390625f + pic);
        }
        unsigned p00 = cvt_pk_bf16(x0[0], x0[1]), p01 = cvt_pk_bf16(x0[2], x0[3]);
        unsigned p10 = cvt_pk_bf16(x1[0], x1[1]), p11 = cvt_pk_bf16(x1[2], x1[3]);
        union { s16x8 v; int u[4]; } b0, b1;
        b0.u[0] = __builtin_amdgcn_ds_bpermute(addr1, (int)p00);
        b0.u[1] = __builtin_amdgcn_ds_bpermute(addr1, (int)p01);
        b0.u[2] = __builtin_amdgcn_ds_bpermute(addr2, (int)p00);
        b0.u[3] = __builtin_amdgcn_ds_bpermute(addr2, (int)p01);
        b1.u[0] = __builtin_amdgcn_ds_bpermute(addr1, (int)p10);
        b1.u[1] = __builtin_amdgcn_ds_bpermute(addr1, (int)p11);
        b1.u[2] = __builtin_amdgcn_ds_bpermute(addr2, (int)p10);
        b1.u[3] = __builtin_amdgcn_ds_bpermute(addr2, (int)p11);
        macc0 = __builtin_amdgcn_mfma_f32_16x16x32_bf16(w2a, b0.v, macc0, 0, 0, 0);
        macc1 = __builtin_amdgcn_mfma_f32_16x16x32_bf16(w2a, b1.v, macc1, 0, 0, 0);
    }
    #pragma unroll
    for (int r = 0; r < 4; r++){
        m_red[wid][n16][grp*4 + r]      = macc0[r];
        m_red[wid][16 + n16][grp*4 + r] = macc1[r];
    }
    __syncthreads();
    #pragma unroll
    for (int t = tid; t < Kk*MD; t += 256){
        int n = t >> 4, f = t & 15;
        float s = m_red[0][n][f] + m_red[1][n][f] + m_red[2][n][f] + m_red[3][n][f];
        m_ws[(size_t)node*(Kk*MD) + t] = silu_f(s + eb2[f]);
    }
}

// ---------------- Kernel N: finish (mi, cw MLP, coors) + node MLP, 8 nodes/block -------------
__global__ __launch_bounds__(256) void finish_kernel(const float* __restrict__ feats,
        const float* __restrict__ coors,
        const float* __restrict__ m_ws, const int* __restrict__ idx_ws,
        const float* __restrict__ cW1, const float* __restrict__ cb1,
        const float* __restrict__ cW2, const float* __restrict__ cb2,
        const float* __restrict__ nW1, const float* __restrict__ nb1,
        const float* __restrict__ nW2, const float* __restrict__ nb2,
        float* __restrict__ out, float* __restrict__ coors_out){
    __shared__ float msh[8][Kk][MD+1];   // 17408 B
    __shared__ float insT[NDI][12];      // 6912 B
    __shared__ float hsdT[NDH][12];      // 12288 B
    int tid = threadIdx.x;
    int node0 = blockIdx.x * 8;
    const float* mp = m_ws + (size_t)node0*(Kk*MD);
    for (int t = tid; t < 8*Kk*MD; t += 256)
        msh[t >> 9][(t >> 4) & 31][t & 15] = mp[t];
    for (int t = tid; t < 8*DIMd; t += 256)
        insT[t & 127][t >> 7] = feats[(size_t)node0*DIMd + t];
    int nl = tid >> 5, n = tid & 31;
    int node = node0 + nl;
    int b = node >> 11;
    int j = idx_ws[node*Kk + n];
    int jg = (b << 11) + j;
    float rx = coors[node*3+0] - coors[jg*3+0];
    float ry = coors[node*3+1] - coors[jg*3+1];
    float rz = coors[node*3+2] - coors[jg*3+2];
    __syncthreads();
    if (tid < 128){
        int m = tid >> 4, f = tid & 15;
        float s = 0.f;
        #pragma unroll
        for (int q = 0; q < Kk; q++) s += msh[m][q][f];
        insT[DIMd + f][m] = s;
    }
    float mv[MD];
    #pragma unroll
    for (int f = 0; f < MD; f++) mv[f] = msh[nl][n][f];
    float p = 0.f;
    #pragma unroll 4
    for (int ug = 0; ug < 16; ug++){
        f32x4 a4 = *(const f32x4*)(cb1 + ug*4);
        #pragma unroll
        for (int f = 0; f < MD; f++){
            f32x4 w4 = *(const f32x4*)(cW1 + f*64 + ug*4);
            a4 += (f32x4){mv[f],mv[f],mv[f],mv[f]} * w4;
        }
        f32x4 c4 = *(const f32x4*)(cW2 + ug*4);
        p += silu_f(a4[0])*c4[0] + silu_f(a4[1])*c4[1]
           + silu_f(a4[2])*c4[2] + silu_f(a4[3])*c4[3];
    }
    float cw = p + cb2[0];
    float vx = cw*rx, vy = cw*ry, vz = cw*rz;
    #pragma unroll
    for (int off = 1; off < 32; off <<= 1){
        vx += __shfl_xor(vx, off); vy += __shfl_xor(vy, off); vz += __shfl_xor(vz, off);
    }
    if (n == 0){
        coors_out[node*3+0] = vx + coors[node*3+0];
        coors_out[node*3+1] = vy + coors[node*3+1];
        coors_out[node*3+2] = vz + coors[node*3+2];
    }
    __syncthreads();
    float bias = nb1[tid];
    f32x2 acc[4];
    #pragma unroll
    for (int q = 0; q < 4; q++) acc[q] = (f32x2){bias, bias};
    for (int k = 0; k < NDI; k++){
        float wv = nW1[(size_t)k*NDH + tid];
        f32x2 w2 = {wv, wv};
        acc[0] += *(const f32x2*)&insT[k][0] * w2;
        acc[1] += *(const f32x2*)&insT[k][2] * w2;
        acc[2] += *(const f32x2*)&insT[k][4] * w2;
        acc[3] += *(const f32x2*)&insT[k][6] * w2;
    }
    #pragma unroll
    for (int q = 0; q < 4; q++) *(f32x2*)&hsdT[tid][2*q] = silu2(acc[q]);
    __syncthreads();
    int c = tid & 127, half = tid >> 7;
    float b2 = nb2[c];
    f32x2 a0 = {b2, b2}, a1 = {b2, b2};
    for (int k = 0; k < NDH; k++){
        float wv = nW2[(size_t)k*DIMd + c];
        f32x2 w2 = {wv, wv};
        a0 += *(const f32x2*)&hsdT[k][half*4]     * w2;
        a1 += *(const f32x2*)&hsdT[k][half*4 + 2] * w2;
    }
    #pragma unroll
    for (int q = 0; q < 4; q++){
        int m = half*4 + q;
        float v = (q < 2) ? a0[q & 1] : a1[q & 1];
        out[(size_t)(node0+m)*DIMd + c] = v + feats[(size_t)(node0+m)*DIMd + c];
    }
}

extern "C" void kernel_launch(void* const* d_in, const int* in_sizes, int n_in,
                              void* d_out, int out_size, void* d_ws, size_t ws_size,
                              hipStream_t stream){
    const float* feats = (const float*)d_in[0];
    const float* coors = (const float*)d_in[1];
    const float* eW1 = (const float*)d_in[2];
    const float* eb1 = (const float*)d_in[3];
    const float* eW2 = (const float*)d_in[4];
    const float* eb2 = (const float*)d_in[5];
    const float* cW1 = (const float*)d_in[6];
    const float* cb1 = (const float*)d_in[7];
    const float* cW2 = (const float*)d_in[8];
    const float* cb2 = (const float*)d_in[9];
    const float* nW1 = (const float*)d_in[10];
    const float* nb1 = (const float*)d_in[11];
    const float* nW2 = (const float*)d_in[12];
    const float* nb2 = (const float*)d_in[13];
    float* out = (float*)d_out;                        // node_out: 4*2048*128
    float* coors_out = out + (size_t)Bb*Nn*DIMd;       // coors_out: 4*2048*3

    char* ws = (char*)d_ws;
    size_t off = 0;
    int*   idx_ws = (int*)(ws + off);   off += (1u<<20);          // 1 MB
    float* dv_ws  = (float*)(ws + off); off += (1u<<20);          // 1 MB
    float* Pd     = (float*)(ws + off); off += 17367040u;         // 8192*530*4
    float* m_ws   = (float*)(ws + off); off += 16777216u;         // 8192*512*4
    unsigned char*  W1F8 = (unsigned char*)(ws + off);  off += 87040u;   // 34*5*512 fp8
    unsigned short* WPF  = (unsigned short*)(ws + off); off += 139264u;  // 34*4*512*2
    unsigned short* W2F2 = (unsigned short*)(ws + off); off += 34816u;   // 34*512*2

    fragw_kernel<<<256, 256, 0, stream>>>(eW1, eW2, W1F8, WPF, W2F2);
    prep_kernel<<<TOPK_BLKS + PMAT_BLKS, 256, 0, stream>>>(coors, feats, WPF, eb1,
                                                           idx_ws, dv_ws, Pd);
    edge_kernel<<<Bb*Nn, 256, 0, stream>>>(feats, eb2, Pd, W1F8, W2F2,
                                           idx_ws, dv_ws, m_ws);
    finish_kernel<<<Bb*Nn/8, 256, 0, stream>>>(feats, coors, m_ws, idx_ws,
                                               cW1, cb1, cW2, cb2,
                                               nW1, nb1, nW2, nb2, out, coors_out);
}